// Round 5
// baseline (34.723 us; speedup 1.0000x reference)
//
#include <hip/hip_runtime.h>
#include <math.h>

#define NF 1024
#define IMS 256
#define TILE 8
#define NT 1024
constexpr float SIGMA = 0.003f;
constexpr float LOG2E = 1.4426950408889634f;
constexpr float PXSZ = 2.0f / (float)IMS;
constexpr float TILE_R = 3.5f * PXSZ;   // max |pixel-center - tile-center|

#if __has_builtin(__builtin_amdgcn_exp2f)
#define EXP2(x) __builtin_amdgcn_exp2f(x)
#else
#define EXP2(x) exp2f(x)
#endif

// One block (4 waves) per 8x8 tile. Each block:
//  A) recomputes all 1024 face edge-coefs from verts/faces (4 faces/thread)
//     into LDS, culling each face against the tile in-registers as it goes;
//  B) rasterizes the survivor list (faces strided across the 4 waves, coefs
//     read from LDS broadcast), with saturation early-exit;
//  C) combines wave partials, computes the squared-diff loss, atomicAdds.
__global__ __launch_bounds__(256) void fused_kernel(const float* __restrict__ verts,
                                                    const int* __restrict__ faces,
                                                    const float* __restrict__ img,
                                                    float* __restrict__ out) {
    __shared__ float4 fc[NF * 3];          // 48 KB face coefficients
    __shared__ unsigned short slist[NF];   // 2 KB survivor list
    __shared__ float part[4][64];          // 1 KB wave partial products
    __shared__ int cnt, cov;
    int t = threadIdx.x;
    int tile = blockIdx.x;
    int ti = tile >> 5, tj = tile & 31;
    if (t == 0) { cnt = 0; cov = 0; }
    __syncthreads();

    // camera constants (verbatim from the validated prep kernel; folds at compile time)
    const float deg2rad = 0.017453292519943295f;
    float e = 0.0f * deg2rad, a = 90.0f * deg2rad;
    float ce = cosf(e), se = sinf(e), ca = cosf(a), sa = sinf(a);
    float ex = 2.732f * ce * sa, ey = 2.732f * se, ez = -2.732f * ce * ca;
    float zn = sqrtf(ex*ex + ey*ey + ez*ez) + 1e-12f;
    float zx = -ex/zn, zy = -ey/zn, zz = -ez/zn;
    float cx = 1.0f*zz, cyv = 0.0f, cz = -1.0f*zx;   // cross(up, zax), up=(0,1,0)
    float xn = sqrtf(cx*cx + cyv*cyv + cz*cz) + 1e-12f;
    float xax_x = cx/xn, xax_y = cyv/xn, xax_z = cz/xn;
    float yx = zy*xax_z - zz*xax_y;
    float yy = zz*xax_x - zx*xax_z;
    float yz = zx*xax_y - zy*xax_x;
    float w = tanf(30.0f * deg2rad);

    float cxn = ((float)(tj * TILE) + 4.0f) * PXSZ - 1.0f;   // tile center (NDC)
    float cyn = -(((float)(ti * TILE) + 4.0f) * PXSZ - 1.0f);

    // ---- phase A: coefs + in-register cull, 4 faces per thread ----
    #pragma unroll
    for (int k = 0; k < NF / 256; ++k) {
        int f = t + 256 * k;
        int idx[3] = {faces[f*3+0], faces[f*3+1], faces[f*3+2]};
        float P[3][2];
        #pragma unroll
        for (int kk = 0; kk < 3; ++kk) {
            float vx = verts[idx[kk]*3+0] - ex;
            float vy = verts[idx[kk]*3+1] - ey;
            float vz = verts[idx[kk]*3+2] - ez;
            float camx = xax_x*vx + xax_y*vy + xax_z*vz;
            float camy = yx*vx + yy*vy + yz*vz;
            float camz = zx*vx + zy*vy + zz*vz;
            float z = fmaxf(camz, 0.01f);
            float invzw = 1.0f / (z * w);
            P[kk][0] = camx * invzw;
            P[kk][1] = camy * invzw;
        }
        float area = (P[1][0]-P[0][0])*(P[2][1]-P[0][1]) - (P[1][1]-P[0][1])*(P[2][0]-P[0][0]);
        float s = (area >= 0.0f) ? 1.0f : -1.0f;
        float o[9];
        #pragma unroll
        for (int kk = 0; kk < 3; ++kk) {
            float x0 = P[kk][0],       y0 = P[kk][1];
            float x1 = P[(kk+1)%3][0], y1 = P[(kk+1)%3][1];
            float ex_ = x1 - x0, ey_ = y1 - y0;
            float len = sqrtf(ex_*ex_ + ey_*ey_);
            float inv = s * (LOG2E / SIGMA) / (len + 1e-12f);
            o[kk*3+0] = -ey_ * inv;
            o[kk*3+1] =  ex_ * inv;
            o[kk*3+2] = (ey_*x0 - ex_*y0) * inv;
        }
        fc[f*3+0] = make_float4(o[0], o[1], o[2], o[3]);
        fc[f*3+1] = make_float4(o[4], o[5], o[6], o[7]);
        fc[f*3+2] = make_float4(o[8], 0.0f, 0.0f, 0.0f);
        // in-register tile cull (identical thresholds to validated round 3/4)
        float d0 = fmaf(o[0], cxn, fmaf(o[1], cyn, o[2]));
        float r0 = (fabsf(o[0]) + fabsf(o[1])) * TILE_R;
        float d1 = fmaf(o[3], cxn, fmaf(o[4], cyn, o[5]));
        float r1 = (fabsf(o[3]) + fabsf(o[4])) * TILE_R;
        float d2 = fmaf(o[6], cxn, fmaf(o[7], cyn, o[8]));
        float r2 = (fabsf(o[6]) + fabsf(o[7])) * TILE_R;
        float t_hi = fminf(d0 + r0, fminf(d1 + r1, d2 + r2));
        float t_lo = fminf(d0 - r0, fminf(d1 - r1, d2 - r2));
        if (t_lo > 130.0f) atomicOr(&cov, 1);            // factor exactly 0 tile-wide
        else if (t_hi > -26.0f) {                         // factor != 1 somewhere in tile
            int pos = atomicAdd(&cnt, 1);
            slist[pos] = (unsigned short)f;
        }
    }
    __syncthreads();

    // ---- phase B: rasterize survivors, faces strided across 4 waves ----
    int lane = t & 63, wave = t >> 6;
    int pi = ti * TILE + (lane >> 3);
    int pj = tj * TILE + (lane & 7);
    float px = ((float)pj + 0.5f) * PXSZ - 1.0f;
    float py = -(((float)pi + 0.5f) * PXSZ - 1.0f);
    float prod = 1.0f;
    int covered = cov;   // uniform after barrier
    if (!covered) {
        int len = cnt;
        int it = 0;
        for (int j = wave; j < len; j += 4) {
            int f = (int)slist[j];
            float4 c0 = fc[f*3+0];    // LDS broadcast (same addr all lanes)
            float4 c1 = fc[f*3+1];
            float4 c2 = fc[f*3+2];
            float d0 = fmaf(c0.x, px, fmaf(c0.y, py, c0.z));
            float d1 = fmaf(c0.w, px, fmaf(c1.x, py, c1.y));
            float d2 = fmaf(c1.z, px, fmaf(c1.w, py, c2.x));
            float tm = fminf(d0, fminf(d1, d2));
            float ef = EXP2(tm);                          // overflow -> inf
            prod *= __builtin_amdgcn_rcpf(1.0f + ef);     // rcp(inf) -> 0
            if ((++it & 7) == 0 && __ballot(prod > 0.0f) == 0ull) break;
        }
    }
    part[wave][lane] = prod;
    __syncthreads();

    // ---- phase C: combine partials + fused loss ----
    if (wave == 0) {
        float pr = covered ? 0.0f
                 : part[0][lane] * part[1][lane] * part[2][lane] * part[3][lane];
        float sil = 1.0f - pr;
        float diff = sil - img[pi * IMS + pj];
        float v = diff * diff;
        #pragma unroll
        for (int o = 32; o > 0; o >>= 1) v += __shfl_down(v, o);
        if (lane == 0) atomicAdd(out, v);
    }
}

extern "C" void kernel_launch(void* const* d_in, const int* in_sizes, int n_in,
                              void* d_out, int out_size, void* d_ws, size_t ws_size,
                              hipStream_t stream) {
    const float* verts = (const float*)d_in[0];
    const float* img   = (const float*)d_in[1];
    const int*   faces = (const int*)d_in[2];
    float* out = (float*)d_out;

    hipMemsetAsync(out, 0, sizeof(float), stream);
    fused_kernel<<<NT, 256, 0, stream>>>(verts, faces, img, out);
}